// Round 1
// baseline (2609.994 us; speedup 1.0000x reference)
//
#include <hip/hip_runtime.h>

// Problem constants
// B=32, N=100, K=20, D=4096, DI=DO=H=512, 4H=2048
// M = B*N = 3200 sample rows, m = b*100 + n
// ws layout (floats):
//   z   : 3200*4096 = 13107200
//   zW  : 3200*512  = 1638400
//   xl  : 3200*1024 = 3276800   (img_feat | w_obj)
//   gin : 3200*2048 = 6553600   (layer0 input-side preacts incl. biases)
//   s1,s2: 3200 each, vb: 512
//   state: 8 * 16384 (H0[2],C0[2],H1[2],C1[2])
// total ~94.3 MiB

__device__ __forceinline__ float sigf(float x) { return 1.0f / (1.0f + __expf(-x)); }

// ---------------- Kernel 1: obj_mask (-> alphas), z = sum_k m_k^2 x_k, s1, s2 ----
__global__ __launch_bounds__(256) void mask_z_kernel(
    const float* __restrict__ x, float* __restrict__ z,
    float* __restrict__ s1, float* __restrict__ s2, float* __restrict__ alphas)
{
  int m = blockIdx.x;            // 0..3199
  int b = m / 100, n = m % 100;
  int t = threadIdx.x;           // 256
  const float* xb = x + (size_t)m * 81920;   // x[b,n,0,0]
  __shared__ float red[4];
  float zv[16];
#pragma unroll
  for (int i = 0; i < 16; ++i) zv[i] = 0.f;
  float s1v = 0.f, s2v = 0.f;
  for (int k = 1; k < 20; ++k) {
    const float4* row = (const float4*)(xb + (size_t)k * 4096);
    float4 v0 = row[t], v1 = row[t + 256], v2 = row[t + 512], v3 = row[t + 768];
    float ps = v0.x + v0.y + v0.z + v0.w + v1.x + v1.y + v1.z + v1.w
             + v2.x + v2.y + v2.z + v2.w + v3.x + v3.y + v3.z + v3.w;
#pragma unroll
    for (int off = 32; off >= 1; off >>= 1) ps += __shfl_down(ps, off);
    if ((t & 63) == 0) red[t >> 6] = ps;
    __syncthreads();
    float mk = red[0] + red[1] + red[2] + red[3];
    __syncthreads();
    float mk2 = mk * mk;
    s1v += mk; s2v += mk2;
    if (t == 0) alphas[((size_t)n * 32 + (size_t)b) * 19 + (k - 1)] = mk;
    zv[0] += mk2 * v0.x; zv[1] += mk2 * v0.y; zv[2] += mk2 * v0.z; zv[3] += mk2 * v0.w;
    zv[4] += mk2 * v1.x; zv[5] += mk2 * v1.y; zv[6] += mk2 * v1.z; zv[7] += mk2 * v1.w;
    zv[8] += mk2 * v2.x; zv[9] += mk2 * v2.y; zv[10] += mk2 * v2.z; zv[11] += mk2 * v2.w;
    zv[12] += mk2 * v3.x; zv[13] += mk2 * v3.y; zv[14] += mk2 * v3.z; zv[15] += mk2 * v3.w;
  }
  float4* zr = (float4*)(z + (size_t)m * 4096);
  zr[t]       = make_float4(zv[0], zv[1], zv[2], zv[3]);
  zr[t + 256] = make_float4(zv[4], zv[5], zv[6], zv[7]);
  zr[t + 512] = make_float4(zv[8], zv[9], zv[10], zv[11]);
  zr[t + 768] = make_float4(zv[12], zv[13], zv[14], zv[15]);
  if (t == 0) { s1[m] = s1v; s2[m] = s2v; }
}

// ---------------- tiny: vb[j] = sum_i W_obj2[j,i] * b_obj[i] --------------------
__global__ void colvec_kernel(const float* __restrict__ W2,
                              const float* __restrict__ bo, float* __restrict__ vb)
{
  int j = blockIdx.x * 256 + threadIdx.x;
  if (j < 512) {
    float s = 0.f;
    for (int i = 0; i < 512; ++i) s += W2[(size_t)j * 512 + i] * bo[i];
    vb[j] = s;
  }
}

// ---------------- fp32 GEMM: C[m,n] = sum_k A[m,k]*W[n,k] + epilogue -----------
// BM=128, BN=64, BK=16, 256 threads, 8x4 per thread. M,N exact multiples.
__global__ __launch_bounds__(256) void gemm_atb(
    const float* __restrict__ A, int lda,
    const float* __restrict__ W, int K,
    float* __restrict__ C, int ldc,
    const float* __restrict__ bias1, const float* __restrict__ bias2,
    const float* __restrict__ rs1, const float* __restrict__ cv1,
    const float* __restrict__ rs2, const float* __restrict__ cv2)
{
  __shared__ __align__(16) float As[16][132];
  __shared__ __align__(16) float Ws[16][68];
  int t = threadIdx.x;
  int m0 = blockIdx.x * 128, n0 = blockIdx.y * 64;
  int ra = t >> 1, ka = (t & 1) * 8;
  int rw = t >> 2, kw = (t & 3) * 4;
  int r0 = (t >> 4) * 8, c0 = (t & 15) * 4;
  float acc[8][4];
#pragma unroll
  for (int i = 0; i < 8; ++i)
#pragma unroll
    for (int j = 0; j < 4; ++j) acc[i][j] = 0.f;

  const float* Arow = A + (size_t)(m0 + ra) * lda;
  const float* Wrow = W + (size_t)(n0 + rw) * K;
  float4 a0 = *(const float4*)(Arow + ka);
  float4 a1 = *(const float4*)(Arow + ka + 4);
  float4 w0 = *(const float4*)(Wrow + kw);

  for (int k0 = 0; k0 < K; k0 += 16) {
    As[ka + 0][ra] = a0.x; As[ka + 1][ra] = a0.y; As[ka + 2][ra] = a0.z; As[ka + 3][ra] = a0.w;
    As[ka + 4][ra] = a1.x; As[ka + 5][ra] = a1.y; As[ka + 6][ra] = a1.z; As[ka + 7][ra] = a1.w;
    Ws[kw + 0][rw] = w0.x; Ws[kw + 1][rw] = w0.y; Ws[kw + 2][rw] = w0.z; Ws[kw + 3][rw] = w0.w;
    __syncthreads();
    float4 na0 = a0, na1 = a1, nw0 = w0;
    if (k0 + 16 < K) {
      na0 = *(const float4*)(Arow + k0 + 16 + ka);
      na1 = *(const float4*)(Arow + k0 + 16 + ka + 4);
      nw0 = *(const float4*)(Wrow + k0 + 16 + kw);
    }
#pragma unroll
    for (int kk = 0; kk < 16; ++kk) {
      float4 xa = *(const float4*)&As[kk][r0];
      float4 xb = *(const float4*)&As[kk][r0 + 4];
      float4 wv = *(const float4*)&Ws[kk][c0];
      float av[8] = {xa.x, xa.y, xa.z, xa.w, xb.x, xb.y, xb.z, xb.w};
      float wj[4] = {wv.x, wv.y, wv.z, wv.w};
#pragma unroll
      for (int i = 0; i < 8; ++i)
#pragma unroll
        for (int j = 0; j < 4; ++j) acc[i][j] += av[i] * wj[j];
    }
    __syncthreads();
    a0 = na0; a1 = na1; w0 = nw0;
  }
#pragma unroll
  for (int i = 0; i < 8; ++i) {
    int m = m0 + r0 + i;
    float r1v = rs1 ? rs1[m] : 0.f;
    float r2v = rs2 ? rs2[m] : 0.f;
#pragma unroll
    for (int j = 0; j < 4; ++j) {
      int n = n0 + c0 + j;
      float v = acc[i][j];
      if (bias1) v += bias1[n];
      if (bias2) v += bias2[n];
      if (cv1) v += r1v * cv1[n];
      if (cv2) v += r2v * cv2[n];
      C[(size_t)m * ldc + n] = v;
    }
  }
}

// ---------------- LSTM phase kernel -------------------------------------------
// grid 512: bid<256 -> partA (layer0, 2 units each, K=512),
//           bid>=256 -> partB (layer1, 2 units each, K=1024).
// Phase p: partA computes h0[p] (p<=99); partB computes h1[p-1] (1<=p<=100);
//          WG0 also computes pred[p-2] from h1[p-2] (p>=2).
__global__ __launch_bounds__(256) void lstm_phase(
    const float* __restrict__ gin,
    const float* __restrict__ Whh0,
    const float* __restrict__ Wih1,
    const float* __restrict__ Whh1,
    const float* __restrict__ b_ih1, const float* __restrict__ b_hh1,
    const float* __restrict__ Wout, const float* __restrict__ bout,
    const float* __restrict__ hA_prev, const float* __restrict__ cA_prev,
    float* __restrict__ hA_cur, float* __restrict__ cA_cur,
    const float* __restrict__ h1_prev, const float* __restrict__ c1_prev,
    float* __restrict__ h1_cur, float* __restrict__ c1_cur,
    float* __restrict__ preds, int p)
{
  __shared__ __align__(16) float lds[8 * 1024 + 1024];  // weights + 1024 scratch
  int bid = blockIdx.x, t = threadIdx.x;
  bool isA = bid < 256;
  int wg = isA ? bid : bid - 256;

  // ---- stage weight slice into LDS with XOR(k4,row) swizzle (conflict-free b128)
  {
    int r = t >> 5, c = t & 31;                      // 8 rows x 32 threads
    int grow = (r >> 1) * 512 + wg * 2 + (r & 1);    // gate-major global row
    if (isA) {
      const float4* src = (const float4*)(Whh0 + (size_t)grow * 512);
#pragma unroll
      for (int i = 0; i < 4; ++i) {
        int k4 = i * 32 + c;                         // 0..127
        *(float4*)&lds[r * 512 + ((k4 ^ r) << 2)] = src[k4];
      }
    } else {
      const float4* sih = (const float4*)(Wih1 + (size_t)grow * 512);
      const float4* shh = (const float4*)(Whh1 + (size_t)grow * 512);
#pragma unroll
      for (int i = 0; i < 8; ++i) {
        int k4g = i * 32 + c;                        // 0..255
        int half = k4g >> 7;
        int k4 = k4g & 127;
        float4 v = half ? shh[k4] : sih[k4];
        *(float4*)&lds[r * 1024 + half * 512 + ((k4 ^ r) << 2)] = v;
      }
    }
  }
  __syncthreads();

  bool active = isA ? (p <= 99) : (p >= 1 && p <= 100);
  int tc = t & 7, bg = (t >> 3) & 7, ks = t >> 6;
  int b0 = bg * 4;
  float a0 = 0.f, a1 = 0.f, a2 = 0.f, a3 = 0.f;

  if (active) {
    if (isA) {
      int base = tc * 512;
      const float* h = hA_prev;
#pragma unroll 4
      for (int kk = 0; kk < 32; ++kk) {
        int k4 = ks * 32 + kk;
        float4 w = *(const float4*)&lds[base + ((k4 ^ tc) << 2)];
        const float* hp = h + k4 * 4;
        float4 h0v = *(const float4*)(hp + (b0 + 0) * 512);
        float4 h1v = *(const float4*)(hp + (b0 + 1) * 512);
        float4 h2v = *(const float4*)(hp + (b0 + 2) * 512);
        float4 h3v = *(const float4*)(hp + (b0 + 3) * 512);
        a0 += w.x * h0v.x + w.y * h0v.y + w.z * h0v.z + w.w * h0v.w;
        a1 += w.x * h1v.x + w.y * h1v.y + w.z * h1v.z + w.w * h1v.w;
        a2 += w.x * h2v.x + w.y * h2v.y + w.z * h2v.z + w.w * h2v.w;
        a3 += w.x * h3v.x + w.y * h3v.y + w.z * h3v.z + w.w * h3v.w;
      }
    } else {
      int half = ks >> 1;
      const float* xv = half ? h1_prev : hA_prev;    // [h0[p-1]; h1[p-2]]
      int base = tc * 1024 + half * 512;
#pragma unroll 4
      for (int kk = 0; kk < 64; ++kk) {
        int k4 = (ks & 1) * 64 + kk;
        float4 w = *(const float4*)&lds[base + ((k4 ^ tc) << 2)];
        const float* hp = xv + k4 * 4;
        float4 h0v = *(const float4*)(hp + (b0 + 0) * 512);
        float4 h1v = *(const float4*)(hp + (b0 + 1) * 512);
        float4 h2v = *(const float4*)(hp + (b0 + 2) * 512);
        float4 h3v = *(const float4*)(hp + (b0 + 3) * 512);
        a0 += w.x * h0v.x + w.y * h0v.y + w.z * h0v.z + w.w * h0v.w;
        a1 += w.x * h1v.x + w.y * h1v.y + w.z * h1v.z + w.w * h1v.w;
        a2 += w.x * h2v.x + w.y * h2v.y + w.z * h2v.z + w.w * h2v.w;
        a3 += w.x * h3v.x + w.y * h3v.y + w.z * h3v.z + w.w * h3v.w;
      }
    }
  }
  // ---- reduce 4 k-slices
  float* scratch = lds + 8192;
  if (active && ks > 0) {
    float* sp = scratch + (t - 64) * 4;
    sp[0] = a0; sp[1] = a1; sp[2] = a2; sp[3] = a3;
  }
  __syncthreads();
  if (active && t < 64) {
    a0 += scratch[t * 4 + 0] + scratch[(t + 64) * 4 + 0] + scratch[(t + 128) * 4 + 0];
    a1 += scratch[t * 4 + 1] + scratch[(t + 64) * 4 + 1] + scratch[(t + 128) * 4 + 1];
    a2 += scratch[t * 4 + 2] + scratch[(t + 64) * 4 + 2] + scratch[(t + 128) * 4 + 2];
    a3 += scratch[t * 4 + 3] + scratch[(t + 64) * 4 + 3] + scratch[(t + 128) * 4 + 3];
    int grow = (tc >> 1) * 512 + wg * 2 + (tc & 1);
    if (isA) {
      size_t gi = ((size_t)b0 * 100 + (size_t)p) * 2048 + grow;  // stride/b = 204800
      a0 += gin[gi];
      a1 += gin[gi + 204800];
      a2 += gin[gi + 409600];
      a3 += gin[gi + 614400];
    } else {
      float bb = b_ih1[grow] + b_hh1[grow];
      a0 += bb; a1 += bb; a2 += bb; a3 += bb;
    }
    float* gbuf = lds + 8960;
    gbuf[tc * 32 + b0 + 0] = a0;
    gbuf[tc * 32 + b0 + 1] = a1;
    gbuf[tc * 32 + b0 + 2] = a2;
    gbuf[tc * 32 + b0 + 3] = a3;
  }
  __syncthreads();
  // ---- cell update (rows laid out r = g*2 + u)
  if (active && t < 64) {
    const float* gbuf = lds + 8960;
    int u = t & 1, b = t >> 1;
    float giv = gbuf[(0 + u) * 32 + b];
    float gfv = gbuf[(2 + u) * 32 + b];
    float ggv = gbuf[(4 + u) * 32 + b];
    float gov = gbuf[(6 + u) * 32 + b];
    int gu = wg * 2 + u;
    float cp = (isA ? cA_prev : c1_prev)[b * 512 + gu];
    float cn = sigf(gfv) * cp + sigf(giv) * tanhf(ggv);
    float hn = sigf(gov) * tanhf(cn);
    if (isA) { cA_cur[b * 512 + gu] = cn; hA_cur[b * 512 + gu] = hn; }
    else     { c1_cur[b * 512 + gu] = cn; h1_cur[b * 512 + gu] = hn; }
  }
  // ---- pred[p-2] from h1[p-2] (== h1_prev buffer), done by WG0 only
  if (bid == 0 && p >= 2) {
    __syncthreads();
    float* sc = lds + 8192;
    int b = t & 31, k8 = t >> 5;
    const float* hp = h1_prev + b * 512 + k8 * 64;
    const float* wp = Wout + k8 * 64;
    float s = 0.f;
#pragma unroll
    for (int i = 0; i < 64; ++i) s += hp[i] * wp[i];
    sc[k8 * 32 + b] = s;
    __syncthreads();
    if (t < 32) {
      float acc = bout[0];
#pragma unroll
      for (int k8i = 0; k8i < 8; ++k8i) acc += sc[k8i * 32 + t];
      preds[t * 100 + (p - 2)] = acc;
    }
  }
}

// ---------------- launch ------------------------------------------------------
extern "C" void kernel_launch(void* const* d_in, const int* in_sizes, int n_in,
                              void* d_out, int out_size, void* d_ws, size_t ws_size,
                              hipStream_t stream) {
  (void)in_sizes; (void)n_in; (void)out_size; (void)ws_size;
  const float* x      = (const float*)d_in[0];
  const float* W_img  = (const float*)d_in[1];
  const float* b_img  = (const float*)d_in[2];
  const float* W_obj  = (const float*)d_in[3];
  const float* b_obj  = (const float*)d_in[4];
  const float* W_obj2 = (const float*)d_in[5];
  const float* b_obj2 = (const float*)d_in[6];
  // d_in[7] = W_ah, d_in[8] = W_ac : mathematically dead (softmax over size-1 axis)
  const float* W_ih0  = (const float*)d_in[9];
  const float* W_hh0  = (const float*)d_in[10];
  const float* b_ih0  = (const float*)d_in[11];
  const float* b_hh0  = (const float*)d_in[12];
  const float* W_ih1  = (const float*)d_in[13];
  const float* W_hh1  = (const float*)d_in[14];
  const float* b_ih1  = (const float*)d_in[15];
  const float* b_hh1  = (const float*)d_in[16];
  const float* W_out  = (const float*)d_in[17];
  const float* b_out  = (const float*)d_in[18];

  float* out    = (float*)d_out;
  float* alphas = out;            // 60800
  float* preds  = out + 60800;    // 3200

  float* ws  = (float*)d_ws;
  float* z   = ws;                    // 13107200
  float* zW  = z + 13107200;          // 1638400
  float* xl  = zW + 1638400;          // 3276800
  float* gin = xl + 3276800;          // 6553600
  float* s1  = gin + 6553600;         // 3200
  float* s2  = s1 + 3200;             // 3200
  float* vb  = s2 + 3200;             // 512
  float* st  = vb + 512;              // 8*16384 state ping-pong
  float* H0[2] = { st + 0 * 16384, st + 1 * 16384 };
  float* C0[2] = { st + 2 * 16384, st + 3 * 16384 };
  float* H1[2] = { st + 4 * 16384, st + 5 * 16384 };
  float* C1[2] = { st + 6 * 16384, st + 7 * 16384 };

  hipMemsetAsync(st, 0, 8 * 16384 * sizeof(float), stream);

  // Phase A: mask (-> alphas), z, s1, s2
  mask_z_kernel<<<3200, 256, 0, stream>>>(x, z, s1, s2, alphas);
  // vb = W_obj2 @ b_obj
  colvec_kernel<<<2, 256, 0, stream>>>(W_obj2, b_obj, vb);
  // img_feat = x[:,:,0,:] @ W_img^T + b_img  -> xl[:, 0:512]
  gemm_atb<<<dim3(25, 8), 256, 0, stream>>>(x, 81920, W_img, 4096, xl, 1024,
      b_img, nullptr, nullptr, nullptr, nullptr, nullptr);
  // zW = z @ W_obj^T
  gemm_atb<<<dim3(25, 8), 256, 0, stream>>>(z, 4096, W_obj, 4096, zW, 512,
      nullptr, nullptr, nullptr, nullptr, nullptr, nullptr);
  // w_obj = zW @ W_obj2^T + s2*vb + s1*b_obj2 -> xl[:, 512:1024]
  gemm_atb<<<dim3(25, 8), 256, 0, stream>>>(zW, 512, W_obj2, 512, xl + 512, 1024,
      nullptr, nullptr, s2, vb, s1, b_obj2);
  // gin = xl @ W_ih0^T + b_ih0 + b_hh0
  gemm_atb<<<dim3(25, 32), 256, 0, stream>>>(xl, 1024, W_ih0, 1024, gin, 2048,
      b_ih0, b_hh0, nullptr, nullptr, nullptr, nullptr);

  // Recurrence: phase p computes h0[p] || h1[p-1] || pred[p-2]
  for (int p = 0; p <= 101; ++p) {
    const float* haP = H0[(p + 1) & 1];
    const float* caP = C0[(p + 1) & 1];
    float* haC = H0[p & 1];
    float* caC = C0[p & 1];
    const float* h1P = H1[p & 1];
    const float* c1P = C1[p & 1];
    float* h1C = H1[(p + 1) & 1];
    float* c1C = C1[(p + 1) & 1];
    lstm_phase<<<512, 256, 0, stream>>>(gin, W_hh0, W_ih1, W_hh1, b_ih1, b_hh1,
        W_out, b_out, haP, caP, haC, caC, h1P, c1P, h1C, c1C, preds, p);
  }
}